// Round 1
// baseline (103.702 us; speedup 1.0000x reference)
//
#include <hip/hip_runtime.h>
#include <hip/hip_bf16.h>

typedef __attribute__((ext_vector_type(8))) short short8;
typedef __attribute__((ext_vector_type(4))) short short4v;
typedef __attribute__((ext_vector_type(4))) float f32x4;
typedef __attribute__((ext_vector_type(8))) __bf16 bf16x8;

#define BB 8
#define CC 64
#define NN 65536        // H*W = 256*256
#define SPLIT1 128      // k1 blocks per batch
#define COLS1 (NN / SPLIT1)   // 512 cols per k1 block
#define TILE_N 256
#define SPLIT3 128      // k3 blocks per batch (512 cols each)

__device__ inline short f2bf(float f) {
    __hip_bfloat16 h = __float2bfloat16(f);
    return __builtin_bit_cast(short, h);
}

// --- MFMA wrapper: tolerate either short8 or bf16x8 builtin signature ---
template <typename V>
__device__ inline auto mfma_bf16_impl(V a, V b, f32x4 c, int)
    -> decltype(__builtin_amdgcn_mfma_f32_16x16x32_bf16(a, b, c, 0, 0, 0)) {
    return __builtin_amdgcn_mfma_f32_16x16x32_bf16(a, b, c, 0, 0, 0);
}
template <typename V>
__device__ inline f32x4 mfma_bf16_impl(V a, V b, f32x4 c, long) {
    bf16x8 a2 = __builtin_bit_cast(bf16x8, a);
    bf16x8 b2 = __builtin_bit_cast(bf16x8, b);
    return __builtin_amdgcn_mfma_f32_16x16x32_bf16(a2, b2, c, 0, 0, 0);
}
__device__ inline f32x4 mfma16(short8 a, short8 b, f32x4 c) {
    return mfma_bf16_impl(a, b, c, 0);
}

// ---------------- Kernel 1: partial Gram (bf16 MFMA) + partial channel sums --
__global__ __launch_bounds__(256) void k1_gram(const float* __restrict__ x,
                                               float* __restrict__ partialG,
                                               float* __restrict__ partialS) {
    __shared__ unsigned short tile[CC * TILE_N];   // 32 KB, XOR-swizzled
    const int blk  = blockIdx.x;
    const int b    = blk / SPLIT1;
    const int s    = blk % SPLIT1;
    const int tid  = threadIdx.x;
    const int w    = tid >> 6;       // wave 0..3
    const int lane = tid & 63;
    const int lg   = lane >> 4;      // lane group 0..3
    const int lr   = lane & 15;

    f32x4 acc[4];
#pragma unroll
    for (int dt = 0; dt < 4; ++dt) acc[dt] = (f32x4){0.f, 0.f, 0.f, 0.f};
    float sums[16];
#pragma unroll
    for (int r = 0; r < 16; ++r) sums[r] = 0.f;

    const int colbase0 = s * COLS1;

    for (int it = 0; it < COLS1 / TILE_N; ++it) {
        const int colbase = colbase0 + it * TILE_N;
        // ---- load 64 x 256 fp32 -> bf16 LDS tile (coalesced float4) ----
#pragma unroll
        for (int r = 0; r < 16; ++r) {
            const int row = w * 16 + r;
            const float4 v = *reinterpret_cast<const float4*>(
                x + ((size_t)(b * CC + row)) * NN + colbase + lane * 4);
            sums[r] += v.x + v.y + v.z + v.w;
            short4v sv;
            sv.x = f2bf(v.x); sv.y = f2bf(v.y); sv.z = f2bf(v.z); sv.w = f2bf(v.w);
            const int idx = ((row << 8) + lane * 4) ^ ((row & 7) << 3);
            *reinterpret_cast<short4v*>(&tile[idx]) = sv;
        }
        __syncthreads();
        // ---- MFMA: wave w computes G[w-tile][dt-tile] over K=256 ----
#pragma unroll
        for (int kk = 0; kk < TILE_N / 32; ++kk) {
            const int col = kk * 32 + lg * 8;
            const int ra  = w * 16 + lr;
            const int ia  = ((ra << 8) + col) ^ ((ra & 7) << 3);
            const short8 af = *reinterpret_cast<const short8*>(&tile[ia]);
#pragma unroll
            for (int dt = 0; dt < 4; ++dt) {
                const int rb = dt * 16 + lr;
                const int ib = ((rb << 8) + col) ^ ((rb & 7) << 3);
                const short8 bf = *reinterpret_cast<const short8*>(&tile[ib]);
                acc[dt] = mfma16(af, bf, acc[dt]);
            }
        }
        __syncthreads();
    }
    // ---- write partial Gram (C/D map: col=lane&15, row=(lane>>4)*4+reg) ----
#pragma unroll
    for (int dt = 0; dt < 4; ++dt) {
#pragma unroll
        for (int r = 0; r < 4; ++r) {
            const int c = w * 16 + lg * 4 + r;
            const int d = dt * 16 + lr;
            partialG[(size_t)blk * 4096 + c * 64 + d] = acc[dt][r];
        }
    }
    // ---- reduce per-row sums across the wave ----
#pragma unroll
    for (int r = 0; r < 16; ++r) {
        float v = sums[r];
        for (int off = 32; off > 0; off >>= 1) v += __shfl_down(v, off);
        if (lane == 0) partialS[blk * CC + w * 16 + r] = v;
    }
}

// ---------------- Kernel 2a: reduce partial Gram over splits ----------------
__global__ __launch_bounds__(256) void k2a_reduceG(const float* __restrict__ partialG,
                                                   float* __restrict__ Gsum) {
    const int gid = blockIdx.x * 256 + threadIdx.x;   // 0..32767
    const int b = gid >> 12;
    const int e = gid & 4095;
    float s = 0.f;
    for (int sp = 0; sp < SPLIT1; ++sp)
        s += partialG[(((size_t)(b * SPLIT1 + sp)) << 12) + e];
    Gsum[gid] = s;
}

// ------- Kernel 2b: means, energy, softmax -> att(bf16) + offsets -----------
__global__ __launch_bounds__(256) void k2b_softmax(const float* __restrict__ partialS,
                                                   const float* __restrict__ Gsum,
                                                   unsigned short* __restrict__ att,
                                                   float* __restrict__ offs) {
    __shared__ float mu[CC];
    __shared__ float ener[CC * CC];
    const int b = blockIdx.x;
    const int tid = threadIdx.x;
    if (tid < CC) {
        float s = 0.f;
        for (int sp = 0; sp < SPLIT1; ++sp) s += partialS[(b * SPLIT1 + sp) * CC + tid];
        mu[tid] = s * (1.f / NN);
    }
    __syncthreads();
    const float inv_n = 1.f / NN;
#pragma unroll
    for (int k = 0; k < 16; ++k) {
        const int e = tid + k * 256;
        const int c = e >> 6, d = e & 63;
        ener[e] = Gsum[(b << 12) + e] * inv_n - mu[c] * mu[d];
    }
    __syncthreads();
    const int w = tid >> 6, lane = tid & 63;
    for (int i = 0; i < 16; ++i) {
        const int c = w * 16 + i;
        const float v = ener[c * 64 + lane];
        float m = v;
        for (int off = 32; off > 0; off >>= 1) m = fmaxf(m, __shfl_xor(m, off));
        const float ev = __expf(v - m);
        float sum = ev;
        for (int off = 32; off > 0; off >>= 1) sum += __shfl_xor(sum, off);
        const float a = ev / sum;
        att[(b << 12) + c * 64 + lane] = (unsigned short)f2bf(a);
        float o = a * mu[lane];
        for (int off = 32; off > 0; off >>= 1) o += __shfl_xor(o, off);
        if (lane == 0) offs[b * CC + c] = o;
    }
}

// ---------------- Kernel 3: out = gamma * (A @ x - offset) ------------------
__global__ __launch_bounds__(256) void k3_apply(const float* __restrict__ x,
                                                const unsigned short* __restrict__ att,
                                                const float* __restrict__ offs,
                                                const float* __restrict__ gamma,
                                                float* __restrict__ out) {
    const int blk  = blockIdx.x;
    const int b    = blk / SPLIT3;
    const int s    = blk % SPLIT3;
    const int tid  = threadIdx.x;
    const int w    = tid >> 6, lane = tid & 63, lg = lane >> 4, lr = lane & 15;
    const float g  = gamma[0];

    // preload attention A-fragments: afr[ct][ks] lane l holds att[ct*16+(l&15)][ks*32+(l>>4)*8 + j]
    short8 afr[4][2];
#pragma unroll
    for (int ct = 0; ct < 4; ++ct)
#pragma unroll
        for (int ks = 0; ks < 2; ++ks)
            afr[ct][ks] = *reinterpret_cast<const short8*>(
                att + (((size_t)b) << 12) + (ct * 16 + lr) * 64 + ks * 32 + lg * 8);

    float offv[4][4];
#pragma unroll
    for (int ct = 0; ct < 4; ++ct)
#pragma unroll
        for (int r = 0; r < 4; ++r)
            offv[ct][r] = offs[b * CC + ct * 16 + lg * 4 + r];

    const int colblock = s * (NN / SPLIT3);
    const int GROUPS = (NN / SPLIT3) / (4 * 64);   // 64-col groups per wave
    for (int itg = 0; itg < GROUPS; ++itg) {
        const int n0 = colblock + (w * GROUPS + itg) * 64;
        f32x4 acc[4][4];   // [phase][ct]; phase = sub-column (lane covers cols lr*4+phase)
#pragma unroll
        for (int ph = 0; ph < 4; ++ph)
#pragma unroll
            for (int ct = 0; ct < 4; ++ct) acc[ph][ct] = (f32x4){0.f, 0.f, 0.f, 0.f};

#pragma unroll
        for (int ks = 0; ks < 2; ++ks) {
            short8 bfr[4];
            const int d0 = ks * 32 + lg * 8;
            const float* xp = x + ((size_t)(b * CC + d0)) * NN + n0 + lr * 4;
#pragma unroll
            for (int j = 0; j < 8; ++j) {
                const float4 v = *reinterpret_cast<const float4*>(xp + (size_t)j * NN);
                bfr[0][j] = f2bf(v.x);
                bfr[1][j] = f2bf(v.y);
                bfr[2][j] = f2bf(v.z);
                bfr[3][j] = f2bf(v.w);
            }
#pragma unroll
            for (int ct = 0; ct < 4; ++ct) {
#pragma unroll
                for (int ph = 0; ph < 4; ++ph)
                    acc[ph][ct] = mfma16(afr[ct][ks], bfr[ph], acc[ph][ct]);
            }
        }
        // store: row c, cols n0 + lr*4 + {0..3}
#pragma unroll
        for (int ct = 0; ct < 4; ++ct) {
#pragma unroll
            for (int r = 0; r < 4; ++r) {
                const int c = ct * 16 + lg * 4 + r;
                const float o = offv[ct][r];
                float4 vs;
                vs.x = g * (acc[0][ct][r] - o);
                vs.y = g * (acc[1][ct][r] - o);
                vs.z = g * (acc[2][ct][r] - o);
                vs.w = g * (acc[3][ct][r] - o);
                *reinterpret_cast<float4*>(out + ((size_t)(b * CC + c)) * NN + n0 + lr * 4) = vs;
            }
        }
    }
}

extern "C" void kernel_launch(void* const* d_in, const int* in_sizes, int n_in,
                              void* d_out, int out_size, void* d_ws, size_t ws_size,
                              hipStream_t stream) {
    const float* x     = (const float*)d_in[0];
    const float* gamma = (const float*)d_in[1];
    float* out = (float*)d_out;

    // Large deterministic partials live at the FRONT of d_out (fully overwritten
    // by k3 afterwards). Only the small att/offs tables (read by k3) use d_ws.
    float* partialG = out;                                   // 8*128*4096 floats (16.8 MB)
    float* partialS = out + (size_t)BB * SPLIT1 * 4096;      // 8*128*64 floats
    float* Gsum     = partialS + BB * SPLIT1 * CC;           // 8*4096 floats
    float* offs     = (float*)d_ws;                          // 512 floats
    unsigned short* att = (unsigned short*)((char*)d_ws + 4096);  // 8*4096 bf16

    k1_gram<<<BB * SPLIT1, 256, 0, stream>>>(x, partialG, partialS);
    k2a_reduceG<<<(BB * 4096) / 256, 256, 0, stream>>>(partialG, Gsum);
    k2b_softmax<<<BB, 256, 0, stream>>>(partialS, Gsum, att, offs);
    k3_apply<<<BB * SPLIT3, 256, 0, stream>>>(x, att, offs, gamma, out);
}

// Round 3
// 93.050 us; speedup vs baseline: 1.1145x; 1.1145x over previous
//
#include <hip/hip_runtime.h>
#include <hip/hip_bf16.h>

typedef __attribute__((ext_vector_type(8))) short short8;
typedef __attribute__((ext_vector_type(4))) short short4v;
typedef __attribute__((ext_vector_type(4))) float f32x4;
typedef __attribute__((ext_vector_type(8))) __bf16 bf16x8;

#define BB 8
#define CC 64
#define NN 65536        // H*W = 256*256
#define SPLIT1 64       // k1 blocks per batch (512 total = 2 blocks/CU)
#define COLS1 (NN / SPLIT1)   // 1024 cols per k1 block
#define TILE_N 256
#define SPLIT3 128      // k3 blocks per batch (512 cols each)

__device__ inline short f2bf(float f) {
    __hip_bfloat16 h = __float2bfloat16(f);
    return __builtin_bit_cast(short, h);
}

// --- MFMA wrapper: tolerate either short8 or bf16x8 builtin signature ---
template <typename V>
__device__ inline auto mfma_bf16_impl(V a, V b, f32x4 c, int)
    -> decltype(__builtin_amdgcn_mfma_f32_16x16x32_bf16(a, b, c, 0, 0, 0)) {
    return __builtin_amdgcn_mfma_f32_16x16x32_bf16(a, b, c, 0, 0, 0);
}
template <typename V>
__device__ inline f32x4 mfma_bf16_impl(V a, V b, f32x4 c, long) {
    bf16x8 a2 = __builtin_bit_cast(bf16x8, a);
    bf16x8 b2 = __builtin_bit_cast(bf16x8, b);
    return __builtin_amdgcn_mfma_f32_16x16x32_bf16(a2, b2, c, 0, 0, 0);
}
__device__ inline f32x4 mfma16(short8 a, short8 b, f32x4 c) {
    return mfma_bf16_impl(a, b, c, 0);
}

// ---------------- Kernel 1: partial Gram (bf16 MFMA) + partial channel sums --
__global__ __launch_bounds__(256) void k1_gram(const float* __restrict__ x,
                                               float* __restrict__ partialG,
                                               float* __restrict__ partialS) {
    __shared__ unsigned short tile[CC * TILE_N];   // 32 KB, XOR-swizzled
    const int blk  = blockIdx.x;
    const int b    = blk / SPLIT1;
    const int s    = blk % SPLIT1;
    const int tid  = threadIdx.x;
    const int w    = tid >> 6;       // wave 0..3
    const int lane = tid & 63;
    const int lg   = lane >> 4;      // lane group 0..3
    const int lr   = lane & 15;

    f32x4 acc[4];
#pragma unroll
    for (int dt = 0; dt < 4; ++dt) acc[dt] = (f32x4){0.f, 0.f, 0.f, 0.f};
    float sums[16];
#pragma unroll
    for (int r = 0; r < 16; ++r) sums[r] = 0.f;

    const int colbase0 = s * COLS1;

    for (int it = 0; it < COLS1 / TILE_N; ++it) {
        const int colbase = colbase0 + it * TILE_N;
        // ---- load 64 x 256 fp32 -> bf16 LDS tile (coalesced float4) ----
#pragma unroll
        for (int r = 0; r < 16; ++r) {
            const int row = w * 16 + r;
            const float4 v = *reinterpret_cast<const float4*>(
                x + ((size_t)(b * CC + row)) * NN + colbase + lane * 4);
            sums[r] += v.x + v.y + v.z + v.w;
            short4v sv;
            sv.x = f2bf(v.x); sv.y = f2bf(v.y); sv.z = f2bf(v.z); sv.w = f2bf(v.w);
            const int idx = ((row << 8) + lane * 4) ^ ((row & 7) << 3);
            *reinterpret_cast<short4v*>(&tile[idx]) = sv;
        }
        __syncthreads();
        // ---- MFMA: wave w computes G[w-tile][dt-tile] over K=256 ----
#pragma unroll
        for (int kk = 0; kk < TILE_N / 32; ++kk) {
            const int col = kk * 32 + lg * 8;
            const int ra  = w * 16 + lr;
            const int ia  = ((ra << 8) + col) ^ ((ra & 7) << 3);
            const short8 af = *reinterpret_cast<const short8*>(&tile[ia]);
#pragma unroll
            for (int dt = 0; dt < 4; ++dt) {
                const int rb = dt * 16 + lr;
                const int ib = ((rb << 8) + col) ^ ((rb & 7) << 3);
                const short8 bf = *reinterpret_cast<const short8*>(&tile[ib]);
                acc[dt] = mfma16(af, bf, acc[dt]);
            }
        }
        __syncthreads();
    }
    // ---- write partial Gram (C/D map: col=lane&15, row=(lane>>4)*4+reg) ----
#pragma unroll
    for (int dt = 0; dt < 4; ++dt) {
#pragma unroll
        for (int r = 0; r < 4; ++r) {
            const int c = w * 16 + lg * 4 + r;
            const int d = dt * 16 + lr;
            partialG[(size_t)blk * 4096 + c * 64 + d] = acc[dt][r];
        }
    }
    // ---- reduce per-row sums across the wave ----
#pragma unroll
    for (int r = 0; r < 16; ++r) {
        float v = sums[r];
        for (int off = 32; off > 0; off >>= 1) v += __shfl_down(v, off);
        if (lane == 0) partialS[blk * CC + w * 16 + r] = v;
    }
}

// ---------------- Kernel 2a: reduce partial Gram over splits ----------------
__global__ __launch_bounds__(256) void k2a_reduceG(const float* __restrict__ partialG,
                                                   float* __restrict__ Gsum) {
    const int gid = blockIdx.x * 256 + threadIdx.x;   // 0..32767
    const int b = gid >> 12;
    const int e = gid & 4095;
    float s = 0.f;
    for (int sp = 0; sp < SPLIT1; ++sp)
        s += partialG[(((size_t)(b * SPLIT1 + sp)) << 12) + e];
    Gsum[gid] = s;
}

// ------- Kernel 2b: means, energy, softmax -> att(bf16) + offsets -----------
__global__ __launch_bounds__(256) void k2b_softmax(const float* __restrict__ partialS,
                                                   const float* __restrict__ Gsum,
                                                   unsigned short* __restrict__ att,
                                                   float* __restrict__ offs) {
    __shared__ float mu[CC];
    __shared__ float ener[CC * CC];
    const int b = blockIdx.x;
    const int tid = threadIdx.x;
    if (tid < CC) {
        float s = 0.f;
        for (int sp = 0; sp < SPLIT1; ++sp) s += partialS[(b * SPLIT1 + sp) * CC + tid];
        mu[tid] = s * (1.f / NN);
    }
    __syncthreads();
    const float inv_n = 1.f / NN;
#pragma unroll
    for (int k = 0; k < 16; ++k) {
        const int e = tid + k * 256;
        const int c = e >> 6, d = e & 63;
        ener[e] = Gsum[(b << 12) + e] * inv_n - mu[c] * mu[d];
    }
    __syncthreads();
    const int w = tid >> 6, lane = tid & 63;
    for (int i = 0; i < 16; ++i) {
        const int c = w * 16 + i;
        const float v = ener[c * 64 + lane];
        float m = v;
        for (int off = 32; off > 0; off >>= 1) m = fmaxf(m, __shfl_xor(m, off));
        const float ev = __expf(v - m);
        float sum = ev;
        for (int off = 32; off > 0; off >>= 1) sum += __shfl_xor(sum, off);
        const float a = ev / sum;
        att[(b << 12) + c * 64 + lane] = (unsigned short)f2bf(a);
        float o = a * mu[lane];
        for (int off = 32; off > 0; off >>= 1) o += __shfl_xor(o, off);
        if (lane == 0) offs[b * CC + c] = o;
    }
}

// ---------------- Kernel 3: out = gamma * (A @ x - offset) ------------------
// Non-temporal stores: keep x resident in Infinity Cache (x is 134 MB < 256 MB
// L3; polluting L3 with 134 MB of output evicts x and forces HBM re-reads).
__global__ __launch_bounds__(256) void k3_apply(const float* __restrict__ x,
                                                const unsigned short* __restrict__ att,
                                                const float* __restrict__ offs,
                                                const float* __restrict__ gamma,
                                                float* __restrict__ out) {
    const int blk  = blockIdx.x;
    const int b    = blk / SPLIT3;
    const int s    = blk % SPLIT3;
    const int tid  = threadIdx.x;
    const int w    = tid >> 6, lane = tid & 63, lg = lane >> 4, lr = lane & 15;
    const float g  = gamma[0];

    // preload attention A-fragments: afr[ct][ks] lane l holds att[ct*16+(l&15)][ks*32+(l>>4)*8 + j]
    short8 afr[4][2];
#pragma unroll
    for (int ct = 0; ct < 4; ++ct)
#pragma unroll
        for (int ks = 0; ks < 2; ++ks)
            afr[ct][ks] = *reinterpret_cast<const short8*>(
                att + (((size_t)b) << 12) + (ct * 16 + lr) * 64 + ks * 32 + lg * 8);

    float offv[4][4];
#pragma unroll
    for (int ct = 0; ct < 4; ++ct)
#pragma unroll
        for (int r = 0; r < 4; ++r)
            offv[ct][r] = offs[b * CC + ct * 16 + lg * 4 + r];

    const int colblock = s * (NN / SPLIT3);
    const int GROUPS = (NN / SPLIT3) / (4 * 64);   // 64-col groups per wave
    for (int itg = 0; itg < GROUPS; ++itg) {
        const int n0 = colblock + (w * GROUPS + itg) * 64;
        f32x4 acc[4][4];   // [phase][ct]; phase = sub-column (lane covers cols lr*4+phase)
#pragma unroll
        for (int ph = 0; ph < 4; ++ph)
#pragma unroll
            for (int ct = 0; ct < 4; ++ct) acc[ph][ct] = (f32x4){0.f, 0.f, 0.f, 0.f};

#pragma unroll
        for (int ks = 0; ks < 2; ++ks) {
            short8 bfr[4];
            const int d0 = ks * 32 + lg * 8;
            const float* xp = x + ((size_t)(b * CC + d0)) * NN + n0 + lr * 4;
#pragma unroll
            for (int j = 0; j < 8; ++j) {
                const float4 v = *reinterpret_cast<const float4*>(xp + (size_t)j * NN);
                bfr[0][j] = f2bf(v.x);
                bfr[1][j] = f2bf(v.y);
                bfr[2][j] = f2bf(v.z);
                bfr[3][j] = f2bf(v.w);
            }
#pragma unroll
            for (int ct = 0; ct < 4; ++ct) {
#pragma unroll
                for (int ph = 0; ph < 4; ++ph)
                    acc[ph][ct] = mfma16(afr[ct][ks], bfr[ph], acc[ph][ct]);
            }
        }
        // store: row c, cols n0 + lr*4 + {0..3}  (non-temporal, ext-vector type)
#pragma unroll
        for (int ct = 0; ct < 4; ++ct) {
#pragma unroll
            for (int r = 0; r < 4; ++r) {
                const int c = ct * 16 + lg * 4 + r;
                const float o = offv[ct][r];
                f32x4 vs;
                vs[0] = g * (acc[0][ct][r] - o);
                vs[1] = g * (acc[1][ct][r] - o);
                vs[2] = g * (acc[2][ct][r] - o);
                vs[3] = g * (acc[3][ct][r] - o);
                __builtin_nontemporal_store(
                    vs, reinterpret_cast<f32x4*>(out + ((size_t)(b * CC + c)) * NN + n0 + lr * 4));
            }
        }
    }
}

extern "C" void kernel_launch(void* const* d_in, const int* in_sizes, int n_in,
                              void* d_out, int out_size, void* d_ws, size_t ws_size,
                              hipStream_t stream) {
    const float* x     = (const float*)d_in[0];
    const float* gamma = (const float*)d_in[1];
    float* out = (float*)d_out;

    // Large deterministic partials live at the FRONT of d_out (fully overwritten
    // by k3 afterwards). Only the small att/offs tables (read by k3) use d_ws.
    float* partialG = out;                                   // 8*64*4096 floats (8.4 MB)
    float* partialS = out + (size_t)BB * SPLIT1 * 4096;      // 8*64*64 floats
    float* Gsum     = partialS + BB * SPLIT1 * CC;           // 8*4096 floats
    float* offs     = (float*)d_ws;                          // 512 floats
    unsigned short* att = (unsigned short*)((char*)d_ws + 4096);  // 8*4096 bf16

    k1_gram<<<BB * SPLIT1, 256, 0, stream>>>(x, partialG, partialS);
    k2a_reduceG<<<(BB * 4096) / 256, 256, 0, stream>>>(partialG, Gsum);
    k2b_softmax<<<BB, 256, 0, stream>>>(partialS, Gsum, att, offs);
    k3_apply<<<BB * SPLIT3, 256, 0, stream>>>(x, att, offs, gamma, out);
}